// Round 1
// baseline (350.837 us; speedup 1.0000x reference)
//
#include <hip/hip_runtime.h>
#include <hip/hip_bf16.h>

#define B_   4
#define C_   256
#define H_   96
#define W_   96
#define HW_  9216        // 96*96
#define CHW_ 2359296     // 256*9216
#define OFFN_ 663552     // 4*18*9216

typedef __attribute__((ext_vector_type(8))) short bf16x8;
typedef __attribute__((ext_vector_type(4))) float f32x4;

__device__ __forceinline__ short f2bf(float f) {
  union { float f; unsigned u; } v; v.f = f;
  unsigned r = v.u + 0x7fff + ((v.u >> 16) & 1);   // RNE, no NaNs in this data
  return (short)(r >> 16);
}

// ---------------- x: NCHW -> NHWC ----------------
__global__ void k_transpose(const float* __restrict__ x, float* __restrict__ xt) {
  __shared__ float tile[32][33];
  const int b = blockIdx.z;
  const int hw0 = blockIdx.x * 32;
  const int c0 = blockIdx.y * 32;
  const int tx = threadIdx.x, ty = threadIdx.y;   // 32 x 8
  const float* xb = x + (size_t)b * CHW_;
  float* xtb = xt + (size_t)b * CHW_;
#pragma unroll
  for (int s = 0; s < 4; ++s)
    tile[ty + s * 8][tx] = xb[(size_t)(c0 + ty + s * 8) * HW_ + hw0 + tx];
  __syncthreads();
#pragma unroll
  for (int s = 0; s < 4; ++s)
    xtb[(size_t)(hw0 + ty + s * 8) * C_ + c0 + tx] = tile[tx][ty + s * 8];
}

// ------- prep: deform_w -> bf16 b-fragments; offset_w -> (c,ij,o18) -------
// w_frag[((kb*16+nf)*64+l)*8+i] = bf16(dw[o][c][kk]),
//   o = nf*16+(l&15), c=(kb&7)*32+(l>>4)*8+i, kk=kb>>3   (k-order: kk*256+c)
__global__ void k_prep(const float* __restrict__ dw, const float* __restrict__ ow,
                       short* __restrict__ wfrag, float* __restrict__ owt) {
  const int idx = blockIdx.x * 256 + threadIdx.x;
  if (idx < 589824) {
    const int i = idx & 7, l = (idx >> 3) & 63, nf = (idx >> 9) & 15, kb = idx >> 13;
    const int o = nf * 16 + (l & 15);
    const int c = (kb & 7) * 32 + (l >> 4) * 8 + i;
    const int kk = kb >> 3;
    wfrag[idx] = f2bf(dw[(size_t)(o * 256 + c) * 9 + kk]);
  } else {
    const int j = idx - 589824;
    if (j < 41472) {
      const int o = j % 18, r = j / 18;           // r = c*9 + ij
      owt[(size_t)r * 18 + o] = ow[(size_t)(o * 256 + (r / 9)) * 9 + (r % 9)];
    }
  }
}

// ---------------- offset conv (fp32, c split into 4 partials) ----------------
__global__ __launch_bounds__(256) void k_offconv(const float* __restrict__ x,
                                                 const float* __restrict__ owt,
                                                 float* __restrict__ part) {
  const int pix = blockIdx.x * 256 + threadIdx.x;   // 0..36863
  const int cc = blockIdx.y;                        // 0..3
  const int b = pix / HW_, rem = pix % HW_;
  const int ho = rem / 96, wo = rem % 96;
  float acc[18];
#pragma unroll
  for (int o = 0; o < 18; ++o) acc[o] = 0.f;
  const float* xb = x + (size_t)b * CHW_;
  for (int c = cc * 64; c < cc * 64 + 64; ++c) {
    const float* xc = xb + (size_t)c * HW_;
    const float* wc = owt + (size_t)c * 9 * 18;
#pragma unroll
    for (int i = 0; i < 3; ++i) {
      const int y = ho + i - 1;
      if ((unsigned)y >= 96u) continue;
#pragma unroll
      for (int j = 0; j < 3; ++j) {
        const int xx = wo + j - 1;
        if ((unsigned)xx >= 96u) continue;
        const float v = xc[y * 96 + xx];
        const float* wp = wc + (i * 3 + j) * 18;
#pragma unroll
        for (int o = 0; o < 18; ++o) acc[o] += v * wp[o];
      }
    }
  }
  float* pp = part + (size_t)cc * OFFN_ + (size_t)b * 18 * HW_ + rem;
#pragma unroll
  for (int o = 0; o < 18; ++o) pp[(size_t)o * HW_] = acc[o];
}

// ---------------- reduce partials + bias ----------------
__global__ void k_redoff(const float* __restrict__ part, const float* __restrict__ ob,
                         float* __restrict__ offs) {
  const int idx = blockIdx.x * 256 + threadIdx.x;   // < 663552
  float s = part[idx] + part[OFFN_ + idx] + part[2 * OFFN_ + idx] + part[3 * OFFN_ + idx];
  offs[idx] = s + ob[(idx / HW_) % 18];
}

// ---------------- deformable conv: gather + bf16 MFMA GEMM ----------------
// Block: 64 pixels (2 ho x 32 wo) x all 256 outputs. 4 waves, each 4 n-frags.
__global__ __launch_bounds__(256) void k_deform(
    const float* __restrict__ xt, const short* __restrict__ wfrag,
    const float* __restrict__ offs, const float* __restrict__ bias,
    float* __restrict__ out) {
  __shared__ float4 mw[576];
  __shared__ int4 mi[576];
  __shared__ short vals[64 * 40];   // 64 rows x 32 bf16, row stride 40 (80B)

  const int tid = threadIdx.x;
  const int blk = blockIdx.x;
  const int b = blk / 144;
  const int r = blk % 144;
  const int ho0 = (r / 3) * 2;
  const int wo0 = (r % 3) * 32;

  // ---- per-block sampling metadata: 9 kk x 64 pixels ----
  for (int u = tid; u < 576; u += 256) {
    const int kk = u >> 6;
    const int m = u & 63;
    const int ho = ho0 + (m >> 5);
    const int wo = wo0 + (m & 31);
    const int base = ho * 96 + wo;
    const float dy = offs[(size_t)(b * 18 + 2 * kk) * HW_ + base];
    const float dx = offs[(size_t)(b * 18 + 2 * kk + 1) * HW_ + base];
    const float py = (float)(ho - 1 + kk / 3) + dy;
    const float px = (float)(wo - 1 + kk % 3) + dx;
    const float y0f = floorf(py), x0f = floorf(px);
    const float ty = py - y0f, tx = px - x0f;
    const int y0 = (int)y0f, x0 = (int)x0f;
    const int y1 = y0 + 1, x1 = x0 + 1;
    const float vy0 = ((unsigned)y0 < 96u) ? 1.f : 0.f;
    const float vy1 = ((unsigned)y1 < 96u) ? 1.f : 0.f;
    const float vx0 = ((unsigned)x0 < 96u) ? 1.f : 0.f;
    const float vx1 = ((unsigned)x1 < 96u) ? 1.f : 0.f;
    const float oy = 1.f - ty, ox = 1.f - tx;
    float4 w4;
    w4.x = oy * ox * vy0 * vx0;
    w4.y = oy * tx * vy0 * vx1;
    w4.z = ty * ox * vy1 * vx0;
    w4.w = ty * tx * vy1 * vx1;
    const int cy0 = min(max(y0, 0), 95), cy1 = min(max(y1, 0), 95);
    const int cx0 = min(max(x0, 0), 95), cx1 = min(max(x1, 0), 95);
    int4 i4;
    i4.x = (cy0 * 96 + cx0) * 256;
    i4.y = (cy0 * 96 + cx1) * 256;
    i4.z = (cy1 * 96 + cx0) * 256;
    i4.w = (cy1 * 96 + cx1) * 256;
    mw[u] = w4; mi[u] = i4;
  }
  __syncthreads();

  const float* xb = xt + (size_t)b * CHW_;
  const int lane = tid & 63;
  const int wave = tid >> 6;
  const int ms = tid >> 3;    // staging row (task 0)
  const int q = tid & 7;      // staging c-quad

  f32x4 acc[4][4];
#pragma unroll
  for (int a = 0; a < 4; ++a)
#pragma unroll
    for (int bb = 0; bb < 4; ++bb) acc[a][bb] = (f32x4){0.f, 0.f, 0.f, 0.f};

  for (int kb = 0; kb < 72; ++kb) {
    const int kk = kb >> 3;
    const int c0 = (kb & 7) << 5;
    // ---- stage A-tile: val[64][32] in bf16 (2 tasks/thread) ----
#pragma unroll
    for (int t2 = 0; t2 < 2; ++t2) {
      const int msx = ms + t2 * 32;
      const float4 w4 = mw[kk * 64 + msx];
      const int4 i4 = mi[kk * 64 + msx];
      const int c = c0 + q * 4;
      const float4 g00 = *(const float4*)(xb + i4.x + c);
      const float4 g01 = *(const float4*)(xb + i4.y + c);
      const float4 g10 = *(const float4*)(xb + i4.z + c);
      const float4 g11 = *(const float4*)(xb + i4.w + c);
      short4 s4;
      s4.x = f2bf(w4.x * g00.x + w4.y * g01.x + w4.z * g10.x + w4.w * g11.x);
      s4.y = f2bf(w4.x * g00.y + w4.y * g01.y + w4.z * g10.y + w4.w * g11.y);
      s4.z = f2bf(w4.x * g00.z + w4.y * g01.z + w4.z * g10.z + w4.w * g11.z);
      s4.w = f2bf(w4.x * g00.w + w4.y * g01.w + w4.z * g10.w + w4.w * g11.w);
      *reinterpret_cast<short4*>(&vals[msx * 40 + q * 4]) = s4;
    }
    // ---- B-fragments straight from global (coalesced 16B/lane) ----
    bf16x8 bfr[4];
    const size_t wbase = ((size_t)(kb * 16 + wave * 4) * 64 + lane) * 8;
#pragma unroll
    for (int j = 0; j < 4; ++j)
      bfr[j] = *(const bf16x8*)(wfrag + wbase + (size_t)j * 512);
    __syncthreads();
    // ---- A-fragments from LDS + MFMA ----
#pragma unroll
    for (int mf = 0; mf < 4; ++mf) {
      const int row = mf * 16 + (lane & 15);
      const bf16x8 af = *(const bf16x8*)(&vals[row * 40 + (lane >> 4) * 8]);
#pragma unroll
      for (int j = 0; j < 4; ++j)
        acc[mf][j] = __builtin_amdgcn_mfma_f32_16x16x32_bf16(af, bfr[j], acc[mf][j], 0, 0, 0);
    }
    __syncthreads();
  }

  // ---- epilogue: D rows are 4 consecutive wo -> float4 stores ----
  const int col = lane & 15;
  const int rg = lane >> 4;
#pragma unroll
  for (int mf = 0; mf < 4; ++mf) {
    const int m = mf * 16 + rg * 4;
    const int ho = ho0 + (m >> 5);
    const int wo = wo0 + (m & 31);
#pragma unroll
    for (int j = 0; j < 4; ++j) {
      const int o = wave * 64 + j * 16 + col;
      const float bv = bias[o];
      float4 v;
      v.x = acc[mf][j][0] + bv;
      v.y = acc[mf][j][1] + bv;
      v.z = acc[mf][j][2] + bv;
      v.w = acc[mf][j][3] + bv;
      *(float4*)(out + (size_t)(b * 256 + o) * HW_ + ho * 96 + wo) = v;
    }
  }
}

extern "C" void kernel_launch(void* const* d_in, const int* in_sizes, int n_in,
                              void* d_out, int out_size, void* d_ws, size_t ws_size,
                              hipStream_t stream) {
  const float* x  = (const float*)d_in[0];
  const float* ow = (const float*)d_in[1];
  const float* ob = (const float*)d_in[2];
  const float* dw = (const float*)d_in[3];
  const float* db = (const float*)d_in[4];
  float* out = (float*)d_out;
  float* ws = (float*)d_ws;

  float* xt    = ws;                        // 9,437,184 f
  float* owt   = ws + 9437184;              //    41,472 f
  float* part  = ws + 9478656;              // 2,654,208 f
  float* offs  = ws + 12132864;             //   663,552 f
  short* wfrag = (short*)(ws + 12796416);   //   589,824 bf16  (total ~52.4 MB)

  hipLaunchKernelGGL(k_transpose, dim3(288, 8, 4), dim3(32, 8, 1), 0, stream, x, xt);
  hipLaunchKernelGGL(k_prep, dim3(2466), dim3(256), 0, stream, dw, ow, wfrag, owt);
  hipLaunchKernelGGL(k_offconv, dim3(144, 4), dim3(256), 0, stream, x, owt, part);
  hipLaunchKernelGGL(k_redoff, dim3(2592), dim3(256), 0, stream, part, ob, offs);
  hipLaunchKernelGGL(k_deform, dim3(576), dim3(256), 0, stream, xt, wfrag, offs, db, out);
}

// Round 3
// 210.590 us; speedup vs baseline: 1.6660x; 1.6660x over previous
//
#include <hip/hip_runtime.h>
#include <hip/hip_bf16.h>

#define HW_  9216        // 96*96
#define CHW_ 2359296     // 256*9216

typedef __attribute__((ext_vector_type(8))) short bf16x8;
typedef __attribute__((ext_vector_type(4))) float f32x4;

__device__ __forceinline__ short f2bf(float f) {
  union { float f; unsigned u; } v; v.f = f;
  unsigned r = v.u + 0x7fff + ((v.u >> 16) & 1);   // RNE, no NaNs in this data
  return (short)(r >> 16);
}

// ---------------- x: NCHW -> NHWC ----------------
__global__ void k_transpose2(const float* __restrict__ x, float* __restrict__ xt) {
  __shared__ float tile[32][33];
  const int b = blockIdx.z;
  const int hw0 = blockIdx.x * 32;
  const int c0 = blockIdx.y * 32;
  const int tx = threadIdx.x, ty = threadIdx.y;   // 32 x 8
  const float* xb = x + (size_t)b * CHW_;
  float* xtb = xt + (size_t)b * CHW_;
#pragma unroll
  for (int s = 0; s < 4; ++s)
    tile[ty + s * 8][tx] = xb[(size_t)(c0 + ty + s * 8) * HW_ + hw0 + tx];
  __syncthreads();
#pragma unroll
  for (int s = 0; s < 4; ++s)
    xtb[(size_t)(hw0 + ty + s * 8) * 256 + c0 + tx] = tile[tx][ty + s * 8];
}

// ------- prep: deform_w + offset_w -> bf16 MFMA b-fragment layouts -------
// wfrag[((kb*16+nf)*64+l)*8+i] = bf16(dw[o][c][kk]), o=nf*16+(l&15),
//   c=(kb&7)*32+(l>>4)*8+i, kk=kb>>3
// owfrag[((s*2+nf)*64+l)*8+i] = bf16(ow[o][c][kk]) (0 for o>=18), o=nf*16+(l&15),
//   c=(s&7)*32+(l>>4)*8+i, kk=s>>3
__global__ void k_prep(const float* __restrict__ dw, const float* __restrict__ ow,
                       short* __restrict__ wfrag, short* __restrict__ owfrag) {
  const int idx = blockIdx.x * 256 + threadIdx.x;
  if (idx < 589824) {
    const int i = idx & 7, l = (idx >> 3) & 63, nf = (idx >> 9) & 15, kb = idx >> 13;
    const int o = nf * 16 + (l & 15);
    const int c = (kb & 7) * 32 + (l >> 4) * 8 + i;
    const int kk = kb >> 3;
    wfrag[idx] = f2bf(dw[(size_t)(o * 256 + c) * 9 + kk]);
  } else {
    const int j = idx - 589824;   // < 73728
    const int i = j & 7, l = (j >> 3) & 63, nf = (j >> 9) & 1, s = j >> 10;
    const int o = nf * 16 + (l & 15);
    const int c = ((s & 7) << 5) + ((l >> 4) << 3) + i;
    const int kk = s >> 3;
    owfrag[j] = (o < 18) ? f2bf(ow[(size_t)(o * 256 + c) * 9 + kk]) : (short)0;
  }
}

// ---- fused: offset conv (phase A, MFMA) + metadata (B) + deform GEMM (C) ----
__global__ __launch_bounds__(256) void k_deform(
    const float* __restrict__ xt, const short* __restrict__ wfrag,
    const short* __restrict__ owfrag, const float* __restrict__ ob,
    const float* __restrict__ db, float* __restrict__ out) {
  __shared__ __align__(16) char smem[26624];
  float*  offsLDS = (float*)smem;            // [64][32] f32   (phase A out)
  float4* mw = (float4*)(smem + 8192);       // [576]
  int4*   mi = (int4*)(smem + 17408);        // [576]
  short*  vals = (short*)smem;               // [64][40] bf16  (overlay, phase C)

  const int tid = threadIdx.x;
  const int blk = blockIdx.x;
  const int b = blk / 144;
  const int r = blk % 144;
  const int ho0 = (r / 3) * 2;
  const int wo0 = (r % 3) * 32;
  const float* xb = xt + (size_t)b * CHW_;
  const int lane = tid & 63;
  const int wave = tid >> 6;

  // ---- phase A: offsets for this block's 64 pixels, all in registers ----
  {
    const int mA = wave * 16 + (lane & 15);      // pixel row this lane owns
    const int hoA = ho0 + (mA >> 5);
    const int woA = wo0 + (mA & 31);
    const int coff = (lane >> 4) << 3;           // k-chunk within 32
    f32x4 oa0 = {0.f, 0.f, 0.f, 0.f}, oa1 = {0.f, 0.f, 0.f, 0.f};
#pragma unroll 4
    for (int s = 0; s < 72; ++s) {
      const int kk = s >> 3;
      const int c0 = (s & 7) << 5;
      const int y = hoA - 1 + kk / 3;
      const int x = woA - 1 + kk % 3;
      float4 g0 = {0.f, 0.f, 0.f, 0.f}, g1 = {0.f, 0.f, 0.f, 0.f};
      if ((unsigned)y < 96u && (unsigned)x < 96u) {
        const float* p = xb + ((y * 96 + x) << 8) + c0 + coff;
        g0 = *(const float4*)p;
        g1 = *(const float4*)(p + 4);
      }
      bf16x8 af;
      af[0] = f2bf(g0.x); af[1] = f2bf(g0.y); af[2] = f2bf(g0.z); af[3] = f2bf(g0.w);
      af[4] = f2bf(g1.x); af[5] = f2bf(g1.y); af[6] = f2bf(g1.z); af[7] = f2bf(g1.w);
      const bf16x8 b0 = *(const bf16x8*)(owfrag + (size_t)s * 1024 + lane * 8);
      const bf16x8 b1 = *(const bf16x8*)(owfrag + (size_t)s * 1024 + 512 + lane * 8);
      oa0 = __builtin_amdgcn_mfma_f32_16x16x32_bf16(af, b0, oa0, 0, 0, 0);
      oa1 = __builtin_amdgcn_mfma_f32_16x16x32_bf16(af, b1, oa1, 0, 0, 0);
    }
    const int r0 = wave * 16 + (lane >> 4) * 4;
    const int cc = lane & 15;
#pragma unroll
    for (int j = 0; j < 4; ++j) {
      offsLDS[(r0 + j) * 32 + cc] = oa0[j];
      offsLDS[(r0 + j) * 32 + 16 + cc] = oa1[j];
    }
  }
  __syncthreads();

  // ---- phase B: sampling metadata: 9 kk x 64 pixels ----
  for (int u = tid; u < 576; u += 256) {
    const int kk = u >> 6;
    const int m = u & 63;
    const int ho = ho0 + (m >> 5);
    const int wo = wo0 + (m & 31);
    const float dy = offsLDS[m * 32 + 2 * kk] + ob[2 * kk];
    const float dx = offsLDS[m * 32 + 2 * kk + 1] + ob[2 * kk + 1];
    const float py = (float)(ho - 1 + kk / 3) + dy;
    const float px = (float)(wo - 1 + kk % 3) + dx;
    const float y0f = floorf(py), x0f = floorf(px);
    const float ty = py - y0f, tx = px - x0f;
    const int y0 = (int)y0f, x0 = (int)x0f;
    const int y1 = y0 + 1, x1 = x0 + 1;
    const float vy0 = ((unsigned)y0 < 96u) ? 1.f : 0.f;
    const float vy1 = ((unsigned)y1 < 96u) ? 1.f : 0.f;
    const float vx0 = ((unsigned)x0 < 96u) ? 1.f : 0.f;
    const float vx1 = ((unsigned)x1 < 96u) ? 1.f : 0.f;
    const float oy = 1.f - ty, ox = 1.f - tx;
    float4 w4;
    w4.x = oy * ox * vy0 * vx0;
    w4.y = oy * tx * vy0 * vx1;
    w4.z = ty * ox * vy1 * vx0;
    w4.w = ty * tx * vy1 * vx1;
    const int cy0 = min(max(y0, 0), 95), cy1 = min(max(y1, 0), 95);
    const int cx0 = min(max(x0, 0), 95), cx1 = min(max(x1, 0), 95);
    int4 i4;
    i4.x = (cy0 * 96 + cx0) * 256;
    i4.y = (cy0 * 96 + cx1) * 256;
    i4.z = (cy1 * 96 + cx0) * 256;
    i4.w = (cy1 * 96 + cx1) * 256;
    mw[u] = w4; mi[u] = i4;
  }
  __syncthreads();

  // ---- phase C: deform GEMM ----
  const int ms = tid >> 3;    // staging row (task 0)
  const int q = tid & 7;      // staging c-quad

  f32x4 acc[4][4];
#pragma unroll
  for (int a = 0; a < 4; ++a)
#pragma unroll
    for (int bb = 0; bb < 4; ++bb) acc[a][bb] = (f32x4){0.f, 0.f, 0.f, 0.f};

  for (int kb = 0; kb < 72; ++kb) {
    const int kk = kb >> 3;
    const int c0 = (kb & 7) << 5;
#pragma unroll
    for (int t2 = 0; t2 < 2; ++t2) {
      const int msx = ms + t2 * 32;
      const float4 w4 = mw[kk * 64 + msx];
      const int4 i4 = mi[kk * 64 + msx];
      const int c = c0 + q * 4;
      const float4 g00 = *(const float4*)(xb + i4.x + c);
      const float4 g01 = *(const float4*)(xb + i4.y + c);
      const float4 g10 = *(const float4*)(xb + i4.z + c);
      const float4 g11 = *(const float4*)(xb + i4.w + c);
      short4 s4;
      s4.x = f2bf(w4.x * g00.x + w4.y * g01.x + w4.z * g10.x + w4.w * g11.x);
      s4.y = f2bf(w4.x * g00.y + w4.y * g01.y + w4.z * g10.y + w4.w * g11.y);
      s4.z = f2bf(w4.x * g00.z + w4.y * g01.z + w4.z * g10.z + w4.w * g11.z);
      s4.w = f2bf(w4.x * g00.w + w4.y * g01.w + w4.z * g10.w + w4.w * g11.w);
      *reinterpret_cast<short4*>(&vals[msx * 40 + q * 4]) = s4;
    }
    bf16x8 bfr[4];
    const size_t wbase = ((size_t)(kb * 16 + wave * 4) * 64 + lane) * 8;
#pragma unroll
    for (int j = 0; j < 4; ++j)
      bfr[j] = *(const bf16x8*)(wfrag + wbase + (size_t)j * 512);
    __syncthreads();
#pragma unroll
    for (int mf = 0; mf < 4; ++mf) {
      const int row = mf * 16 + (lane & 15);
      const bf16x8 af = *(const bf16x8*)(&vals[row * 40 + (lane >> 4) * 8]);
#pragma unroll
      for (int j = 0; j < 4; ++j)
        acc[mf][j] = __builtin_amdgcn_mfma_f32_16x16x32_bf16(af, bfr[j], acc[mf][j], 0, 0, 0);
    }
    __syncthreads();
  }

  // ---- epilogue ----
  const int col = lane & 15;
  const int rg = lane >> 4;
#pragma unroll
  for (int mf = 0; mf < 4; ++mf) {
    const int m = mf * 16 + rg * 4;
    const int ho = ho0 + (m >> 5);
    const int wo = wo0 + (m & 31);
#pragma unroll
    for (int j = 0; j < 4; ++j) {
      const int o = wave * 64 + j * 16 + col;
      const float bv = db[o];
      float4 v;
      v.x = acc[mf][j][0] + bv;
      v.y = acc[mf][j][1] + bv;
      v.z = acc[mf][j][2] + bv;
      v.w = acc[mf][j][3] + bv;
      *(float4*)(out + (size_t)(b * 256 + o) * HW_ + ho * 96 + wo) = v;
    }
  }
}

extern "C" void kernel_launch(void* const* d_in, const int* in_sizes, int n_in,
                              void* d_out, int out_size, void* d_ws, size_t ws_size,
                              hipStream_t stream) {
  const float* x  = (const float*)d_in[0];
  const float* ow = (const float*)d_in[1];
  const float* ob = (const float*)d_in[2];
  const float* dw = (const float*)d_in[3];
  const float* db = (const float*)d_in[4];
  float* out = (float*)d_out;
  float* ws = (float*)d_ws;

  float* xt     = ws;                        // 9,437,184 f
  short* wfrag  = (short*)(ws + 9437184);    //   589,824 bf16
  short* owfrag = wfrag + 589824;            //    73,728 bf16   (~39 MB total)

  hipLaunchKernelGGL(k_transpose2, dim3(288, 8, 4), dim3(32, 8, 1), 0, stream, x, xt);
  hipLaunchKernelGGL(k_prep, dim3(2592), dim3(256), 0, stream, dw, ow, wfrag, owfrag);
  hipLaunchKernelGGL(k_deform, dim3(576), dim3(256), 0, stream,
                     xt, wfrag, owfrag, ob, db, out);
}

// Round 4
// 182.640 us; speedup vs baseline: 1.9209x; 1.1530x over previous
//
#include <hip/hip_runtime.h>
#include <hip/hip_bf16.h>

#define HW_  9216        // 96*96
#define CHW_ 2359296     // 256*9216

typedef __attribute__((ext_vector_type(8))) short bf16x8;
typedef __attribute__((ext_vector_type(4))) float f32x4;

__device__ __forceinline__ short f2bf(float f) {
  union { float f; unsigned u; } v; v.f = f;
  unsigned r = v.u + 0x7fff + ((v.u >> 16) & 1);   // RNE, no NaNs in this data
  return (short)(r >> 16);
}

// ---------------- x: NCHW -> NHWC ----------------
__global__ void k_transpose2(const float* __restrict__ x, float* __restrict__ xt) {
  __shared__ float tile[32][33];
  const int b = blockIdx.z;
  const int hw0 = blockIdx.x * 32;
  const int c0 = blockIdx.y * 32;
  const int tx = threadIdx.x, ty = threadIdx.y;   // 32 x 8
  const float* xb = x + (size_t)b * CHW_;
  float* xtb = xt + (size_t)b * CHW_;
#pragma unroll
  for (int s = 0; s < 4; ++s)
    tile[ty + s * 8][tx] = xb[(size_t)(c0 + ty + s * 8) * HW_ + hw0 + tx];
  __syncthreads();
#pragma unroll
  for (int s = 0; s < 4; ++s)
    xtb[(size_t)(hw0 + ty + s * 8) * 256 + c0 + tx] = tile[tx][ty + s * 8];
}

// ------- prep: deform_w + offset_w -> bf16 MFMA b-fragment layouts -------
__global__ void k_prep(const float* __restrict__ dw, const float* __restrict__ ow,
                       short* __restrict__ wfrag, short* __restrict__ owfrag) {
  const int idx = blockIdx.x * 256 + threadIdx.x;
  if (idx < 589824) {
    const int i = idx & 7, l = (idx >> 3) & 63, nf = (idx >> 9) & 15, kb = idx >> 13;
    const int o = nf * 16 + (l & 15);
    const int c = (kb & 7) * 32 + (l >> 4) * 8 + i;
    const int kk = kb >> 3;
    wfrag[idx] = f2bf(dw[(size_t)(o * 256 + c) * 9 + kk]);
  } else {
    const int j = idx - 589824;   // < 73728
    const int i = j & 7, l = (j >> 3) & 63, nf = (j >> 9) & 1, s = j >> 10;
    const int o = nf * 16 + (l & 15);
    const int c = ((s & 7) << 5) + ((l >> 4) << 3) + i;
    const int kk = s >> 3;
    owfrag[j] = (o < 18) ? f2bf(ow[(size_t)(o * 256 + c) * 9 + kk]) : (short)0;
  }
}

// ---- fused: offset conv (phase A, MFMA) + metadata (B) + deform GEMM (C) ----
__global__ __launch_bounds__(256) void k_deform(
    const float* __restrict__ xt, const short* __restrict__ wfrag,
    const short* __restrict__ owfrag, const float* __restrict__ ob,
    const float* __restrict__ db, float* __restrict__ out) {
  __shared__ __align__(16) char smem[28672];
  short*  vals = (short*)smem;               // 2 x [64][40] bf16 (double buffer)
  float*  offsLDS = (float*)smem;            // [64][32] f32 (phase A out, overlay)
  float4* mw = (float4*)(smem + 10240);      // [576]
  int4*   mi = (int4*)(smem + 19456);        // [576]

  const int tid = threadIdx.x;
  // XCD-aware bijective swizzle: 576 blocks = 8 XCDs x 72 contiguous strips
  const int blk0 = blockIdx.x;
  const int blk = (blk0 & 7) * 72 + (blk0 >> 3);
  const int b = blk / 144;
  const int r = blk % 144;
  const int ho0 = (r / 3) * 2;
  const int wo0 = (r % 3) * 32;
  const float* xb = xt + (size_t)b * CHW_;
  const int lane = tid & 63;
  const int wave = tid >> 6;

  // ---- phase A: offset conv for this block's 64 pixels (register MFMA) ----
  {
    const int mA = wave * 16 + (lane & 15);
    const int hoA = ho0 + (mA >> 5);
    const int woA = wo0 + (mA & 31);
    const int coff = (lane >> 4) << 3;
    f32x4 oa0 = {0.f, 0.f, 0.f, 0.f}, oa1 = {0.f, 0.f, 0.f, 0.f};
#pragma unroll 4
    for (int s = 0; s < 72; ++s) {
      const int kk = s >> 3;
      const int c0 = (s & 7) << 5;
      const int y = hoA - 1 + kk / 3;
      const int x = woA - 1 + kk % 3;
      float4 g0 = {0.f, 0.f, 0.f, 0.f}, g1 = {0.f, 0.f, 0.f, 0.f};
      if ((unsigned)y < 96u && (unsigned)x < 96u) {
        const float* p = xb + ((y * 96 + x) << 8) + c0 + coff;
        g0 = *(const float4*)p;
        g1 = *(const float4*)(p + 4);
      }
      bf16x8 af;
      af[0] = f2bf(g0.x); af[1] = f2bf(g0.y); af[2] = f2bf(g0.z); af[3] = f2bf(g0.w);
      af[4] = f2bf(g1.x); af[5] = f2bf(g1.y); af[6] = f2bf(g1.z); af[7] = f2bf(g1.w);
      const bf16x8 b0 = *(const bf16x8*)(owfrag + (size_t)s * 1024 + lane * 8);
      const bf16x8 b1 = *(const bf16x8*)(owfrag + (size_t)s * 1024 + 512 + lane * 8);
      oa0 = __builtin_amdgcn_mfma_f32_16x16x32_bf16(af, b0, oa0, 0, 0, 0);
      oa1 = __builtin_amdgcn_mfma_f32_16x16x32_bf16(af, b1, oa1, 0, 0, 0);
    }
    const int r0 = wave * 16 + (lane >> 4) * 4;
    const int cc = lane & 15;
#pragma unroll
    for (int j = 0; j < 4; ++j) {
      offsLDS[(r0 + j) * 32 + cc] = oa0[j];
      offsLDS[(r0 + j) * 32 + 16 + cc] = oa1[j];
    }
  }
  __syncthreads();

  // ---- phase B: sampling metadata: 9 kk x 64 pixels ----
  for (int u = tid; u < 576; u += 256) {
    const int kk = u >> 6;
    const int m = u & 63;
    const int ho = ho0 + (m >> 5);
    const int wo = wo0 + (m & 31);
    const float dy = offsLDS[m * 32 + 2 * kk] + ob[2 * kk];
    const float dx = offsLDS[m * 32 + 2 * kk + 1] + ob[2 * kk + 1];
    const float py = (float)(ho - 1 + kk / 3) + dy;
    const float px = (float)(wo - 1 + kk % 3) + dx;
    const float y0f = floorf(py), x0f = floorf(px);
    const float ty = py - y0f, tx = px - x0f;
    const int y0 = (int)y0f, x0 = (int)x0f;
    const int y1 = y0 + 1, x1 = x0 + 1;
    const float vy0 = ((unsigned)y0 < 96u) ? 1.f : 0.f;
    const float vy1 = ((unsigned)y1 < 96u) ? 1.f : 0.f;
    const float vx0 = ((unsigned)x0 < 96u) ? 1.f : 0.f;
    const float vx1 = ((unsigned)x1 < 96u) ? 1.f : 0.f;
    const float oy = 1.f - ty, ox = 1.f - tx;
    float4 w4;
    w4.x = oy * ox * vy0 * vx0;
    w4.y = oy * tx * vy0 * vx1;
    w4.z = ty * ox * vy1 * vx0;
    w4.w = ty * tx * vy1 * vx1;
    const int cy0 = min(max(y0, 0), 95), cy1 = min(max(y1, 0), 95);
    const int cx0 = min(max(x0, 0), 95), cx1 = min(max(x1, 0), 95);
    int4 i4;
    i4.x = (cy0 * 96 + cx0) * 256;
    i4.y = (cy0 * 96 + cx1) * 256;
    i4.z = (cy1 * 96 + cx0) * 256;
    i4.w = (cy1 * 96 + cx1) * 256;
    mw[u] = w4; mi[u] = i4;
  }
  __syncthreads();

  // ---- phase C: deform GEMM, double-buffered, 1 barrier / K-step ----
  const int ms = tid >> 3;    // staging row
  const int q = tid & 7;      // staging c-quad

  f32x4 acc[4][4];
#pragma unroll
  for (int a = 0; a < 4; ++a)
#pragma unroll
    for (int bb = 0; bb < 4; ++bb) acc[a][bb] = (f32x4){0.f, 0.f, 0.f, 0.f};

  // prologue: stage kb=0 into buf0
#pragma unroll
  for (int t2 = 0; t2 < 2; ++t2) {
    const int msx = ms + t2 * 32;
    const float4 w4 = mw[msx];
    const int4 i4 = mi[msx];
    const int c = q * 4;
    const float4 g00 = *(const float4*)(xb + i4.x + c);
    const float4 g01 = *(const float4*)(xb + i4.y + c);
    const float4 g10 = *(const float4*)(xb + i4.z + c);
    const float4 g11 = *(const float4*)(xb + i4.w + c);
    short4 s4;
    s4.x = f2bf(w4.x * g00.x + w4.y * g01.x + w4.z * g10.x + w4.w * g11.x);
    s4.y = f2bf(w4.x * g00.y + w4.y * g01.y + w4.z * g10.y + w4.w * g11.y);
    s4.z = f2bf(w4.x * g00.z + w4.y * g01.z + w4.z * g10.z + w4.w * g11.z);
    s4.w = f2bf(w4.x * g00.w + w4.y * g01.w + w4.z * g10.w + w4.w * g11.w);
    *reinterpret_cast<short4*>(&vals[msx * 40 + q * 4]) = s4;
  }
  __syncthreads();

  for (int kb = 0; kb < 72; ++kb) {
    const int cur = kb & 1;
    const short* vcur = vals + cur * 2560;
    short* vnxt = vals + (cur ^ 1) * 2560;

    // B-fragments (L2-resident, coalesced 16B/lane)
    bf16x8 bfr[4];
    const size_t wbase = ((size_t)(kb * 16 + wave * 4) * 64 + lane) * 8;
#pragma unroll
    for (int j = 0; j < 4; ++j)
      bfr[j] = *(const bf16x8*)(wfrag + wbase + (size_t)j * 512);

    // issue gathers for kb+1 early (overlap with MFMAs below)
    const int kbn = (kb < 71) ? kb + 1 : kb;
    const int kkn = kbn >> 3;
    const int c0n = (kbn & 7) << 5;
    float4 G[2][4];
    float4 W4[2];
#pragma unroll
    for (int t2 = 0; t2 < 2; ++t2) {
      const int msx = ms + t2 * 32;
      W4[t2] = mw[kkn * 64 + msx];
      const int4 i4 = mi[kkn * 64 + msx];
      const int c = c0n + q * 4;
      G[t2][0] = *(const float4*)(xb + i4.x + c);
      G[t2][1] = *(const float4*)(xb + i4.y + c);
      G[t2][2] = *(const float4*)(xb + i4.z + c);
      G[t2][3] = *(const float4*)(xb + i4.w + c);
    }

    // MFMAs on current buffer
#pragma unroll
    for (int mf = 0; mf < 4; ++mf) {
      const int row = mf * 16 + (lane & 15);
      const bf16x8 af = *(const bf16x8*)(&vcur[row * 40 + (lane >> 4) * 8]);
#pragma unroll
      for (int j = 0; j < 4; ++j)
        acc[mf][j] = __builtin_amdgcn_mfma_f32_16x16x32_bf16(af, bfr[j], acc[mf][j], 0, 0, 0);
    }

    // convert + write next buffer
    if (kb < 71) {
#pragma unroll
      for (int t2 = 0; t2 < 2; ++t2) {
        const int msx = ms + t2 * 32;
        const float4 w4 = W4[t2];
        short4 s4;
        s4.x = f2bf(w4.x * G[t2][0].x + w4.y * G[t2][1].x + w4.z * G[t2][2].x + w4.w * G[t2][3].x);
        s4.y = f2bf(w4.x * G[t2][0].y + w4.y * G[t2][1].y + w4.z * G[t2][2].y + w4.w * G[t2][3].y);
        s4.z = f2bf(w4.x * G[t2][0].z + w4.y * G[t2][1].z + w4.z * G[t2][2].z + w4.w * G[t2][3].z);
        s4.w = f2bf(w4.x * G[t2][0].w + w4.y * G[t2][1].w + w4.z * G[t2][2].w + w4.w * G[t2][3].w);
        *reinterpret_cast<short4*>(&vnxt[msx * 40 + q * 4]) = s4;
      }
    }
    __syncthreads();
  }

  // ---- epilogue ----
  const int col = lane & 15;
  const int rg = lane >> 4;
#pragma unroll
  for (int mf = 0; mf < 4; ++mf) {
    const int m = mf * 16 + rg * 4;
    const int ho = ho0 + (m >> 5);
    const int wo = wo0 + (m & 31);
#pragma unroll
    for (int j = 0; j < 4; ++j) {
      const int o = wave * 64 + j * 16 + col;
      const float bv = db[o];
      float4 v;
      v.x = acc[mf][j][0] + bv;
      v.y = acc[mf][j][1] + bv;
      v.z = acc[mf][j][2] + bv;
      v.w = acc[mf][j][3] + bv;
      *(float4*)(out + (size_t)(b * 256 + o) * HW_ + ho * 96 + wo) = v;
    }
  }
}

extern "C" void kernel_launch(void* const* d_in, const int* in_sizes, int n_in,
                              void* d_out, int out_size, void* d_ws, size_t ws_size,
                              hipStream_t stream) {
  const float* x  = (const float*)d_in[0];
  const float* ow = (const float*)d_in[1];
  const float* ob = (const float*)d_in[2];
  const float* dw = (const float*)d_in[3];
  const float* db = (const float*)d_in[4];
  float* out = (float*)d_out;
  float* ws = (float*)d_ws;

  float* xt     = ws;                        // 9,437,184 f
  short* wfrag  = (short*)(ws + 9437184);    //   589,824 bf16
  short* owfrag = wfrag + 589824;            //    73,728 bf16

  hipLaunchKernelGGL(k_transpose2, dim3(288, 8, 4), dim3(32, 8, 1), 0, stream, x, xt);
  hipLaunchKernelGGL(k_prep, dim3(2592), dim3(256), 0, stream, dw, ow, wfrag, owfrag);
  hipLaunchKernelGGL(k_deform, dim3(576), dim3(256), 0, stream,
                     xt, wfrag, owfrag, ob, db, out);
}

// Round 5
// 155.360 us; speedup vs baseline: 2.2582x; 1.1756x over previous
//
#include <hip/hip_runtime.h>
#include <hip/hip_bf16.h>

#define HW_  9216        // 96*96
#define CHW_ 2359296     // 256*9216

typedef __attribute__((ext_vector_type(8))) short bf16x8;
typedef __attribute__((ext_vector_type(4))) float f32x4;

__device__ __forceinline__ short f2bf(float f) {
  union { float f; unsigned u; } v; v.f = f;
  unsigned r = v.u + 0x7fff + ((v.u >> 16) & 1);   // RNE, no NaNs in this data
  return (short)(r >> 16);
}
__device__ __forceinline__ float bflo(unsigned u) {
  union { unsigned u; float f; } v; v.u = u << 16; return v.f;
}
__device__ __forceinline__ float bfhi(unsigned u) {
  union { unsigned u; float f; } v; v.u = u & 0xffff0000u; return v.f;
}

// ---------------- x: NCHW f32 -> NHWC bf16 ----------------
__global__ void k_transpose2(const float* __restrict__ x, short* __restrict__ xt) {
  __shared__ float tile[32][33];
  const int b = blockIdx.z;
  const int hw0 = blockIdx.x * 32;
  const int c0 = blockIdx.y * 32;
  const int tx = threadIdx.x, ty = threadIdx.y;   // 32 x 8
  const float* xb = x + (size_t)b * CHW_;
  short* xtb = xt + (size_t)b * CHW_;
#pragma unroll
  for (int s = 0; s < 4; ++s)
    tile[ty + s * 8][tx] = xb[(size_t)(c0 + ty + s * 8) * HW_ + hw0 + tx];
  __syncthreads();
  const int tid = ty * 32 + tx;
  const int cp = tid & 15;    // channel pair
  const int hh = tid >> 4;    // 0..15
#pragma unroll
  for (int s = 0; s < 2; ++s) {
    const int hw = hh + s * 16;
    short2 v;
    v.x = f2bf(tile[2 * cp][hw]);
    v.y = f2bf(tile[2 * cp + 1][hw]);
    *(short2*)&xtb[(size_t)(hw0 + hw) * 256 + c0 + 2 * cp] = v;
  }
}

// ------- prep: deform_w + offset_w -> bf16 MFMA b-fragment layouts -------
__global__ void k_prep(const float* __restrict__ dw, const float* __restrict__ ow,
                       short* __restrict__ wfrag, short* __restrict__ owfrag) {
  const int idx = blockIdx.x * 256 + threadIdx.x;
  if (idx < 589824) {
    const int i = idx & 7, l = (idx >> 3) & 63, nf = (idx >> 9) & 15, kb = idx >> 13;
    const int o = nf * 16 + (l & 15);
    const int c = (kb & 7) * 32 + (l >> 4) * 8 + i;
    const int kk = kb >> 3;
    wfrag[idx] = f2bf(dw[(size_t)(o * 256 + c) * 9 + kk]);
  } else {
    const int j = idx - 589824;   // < 73728
    const int i = j & 7, l = (j >> 3) & 63, nf = (j >> 9) & 1, s = j >> 10;
    const int o = nf * 16 + (l & 15);
    const int c = ((s & 7) << 5) + ((l >> 4) << 3) + i;
    const int kk = s >> 3;
    owfrag[j] = (o < 18) ? f2bf(ow[(size_t)(o * 256 + c) * 9 + kk]) : (short)0;
  }
}

// ---- fused: offset conv (phase A, MFMA) + metadata (B) + deform GEMM (C) ----
// 1152 blocks x 128 threads. Block = 1 ho row x 32 wo pixels, all 256 outputs.
__global__ __launch_bounds__(128) void k_deform(
    const short* __restrict__ xt, const short* __restrict__ wfrag,
    const short* __restrict__ owfrag, const float* __restrict__ ob,
    const float* __restrict__ db, float* __restrict__ out) {
  __shared__ __align__(16) char smem[14336];
  short*  vals = (short*)smem;               // 2 x [32][40] bf16 (double buffer)
  float*  offsLDS = (float*)smem;            // [32][32] f32 (phase A out, overlay)
  float4* mw = (float4*)(smem + 5120);       // [288]
  int4*   mi = (int4*)(smem + 9728);         // [288]

  const int tid = threadIdx.x;
  // XCD-aware bijective swizzle: 1152 = 8 XCDs x 144 contiguous strips
  const int blk0 = blockIdx.x;
  const int blk = (blk0 & 7) * 144 + (blk0 >> 3);
  const int b = blk / 288;
  const int r = blk % 288;
  const int ho0 = r / 3;
  const int wo0 = (r % 3) * 32;
  const short* xb = xt + (size_t)b * CHW_;
  const int lane = tid & 63;
  const int wave = tid >> 6;   // 0..1

  // ---- phase A: offset conv for this block's 32 pixels (register MFMA) ----
  {
    const int pA = wave * 16 + (lane & 15);      // pixel 0..31
    const int woA = wo0 + pA;
    const int coff = (lane >> 4) << 3;
    f32x4 oa0 = {0.f, 0.f, 0.f, 0.f}, oa1 = {0.f, 0.f, 0.f, 0.f};
#pragma unroll 4
    for (int s = 0; s < 72; ++s) {
      const int kk = s >> 3;
      const int c0 = (s & 7) << 5;
      const int y = ho0 - 1 + kk / 3;
      const int x = woA - 1 + kk % 3;
      bf16x8 af = {0, 0, 0, 0, 0, 0, 0, 0};
      if ((unsigned)y < 96u && (unsigned)x < 96u)
        af = *(const bf16x8*)(xb + ((y * 96 + x) << 8) + c0 + coff);
      const bf16x8 b0 = *(const bf16x8*)(owfrag + (size_t)s * 1024 + lane * 8);
      const bf16x8 b1 = *(const bf16x8*)(owfrag + (size_t)s * 1024 + 512 + lane * 8);
      oa0 = __builtin_amdgcn_mfma_f32_16x16x32_bf16(af, b0, oa0, 0, 0, 0);
      oa1 = __builtin_amdgcn_mfma_f32_16x16x32_bf16(af, b1, oa1, 0, 0, 0);
    }
    const int r0 = wave * 16 + (lane >> 4) * 4;
    const int cc = lane & 15;
#pragma unroll
    for (int j = 0; j < 4; ++j) {
      offsLDS[(r0 + j) * 32 + cc] = oa0[j];
      offsLDS[(r0 + j) * 32 + 16 + cc] = oa1[j];
    }
  }
  __syncthreads();

  // ---- phase B: sampling metadata: 9 kk x 32 pixels ----
  for (int u = tid; u < 288; u += 128) {
    const int kk = u >> 5;
    const int p = u & 31;
    const int wo = wo0 + p;
    const float dy = offsLDS[p * 32 + 2 * kk] + ob[2 * kk];
    const float dx = offsLDS[p * 32 + 2 * kk + 1] + ob[2 * kk + 1];
    const float py = (float)(ho0 - 1 + kk / 3) + dy;
    const float px = (float)(wo - 1 + kk % 3) + dx;
    const float y0f = floorf(py), x0f = floorf(px);
    const float ty = py - y0f, tx = px - x0f;
    const int y0 = (int)y0f, x0 = (int)x0f;
    const int y1 = y0 + 1, x1 = x0 + 1;
    const float vy0 = ((unsigned)y0 < 96u) ? 1.f : 0.f;
    const float vy1 = ((unsigned)y1 < 96u) ? 1.f : 0.f;
    const float vx0 = ((unsigned)x0 < 96u) ? 1.f : 0.f;
    const float vx1 = ((unsigned)x1 < 96u) ? 1.f : 0.f;
    const float oy = 1.f - ty, ox = 1.f - tx;
    float4 w4;
    w4.x = oy * ox * vy0 * vx0;
    w4.y = oy * tx * vy0 * vx1;
    w4.z = ty * ox * vy1 * vx0;
    w4.w = ty * tx * vy1 * vx1;
    const int cy0 = min(max(y0, 0), 95), cy1 = min(max(y1, 0), 95);
    const int cx0 = min(max(x0, 0), 95), cx1 = min(max(x1, 0), 95);
    int4 i4;
    i4.x = (cy0 * 96 + cx0) << 8;
    i4.y = (cy0 * 96 + cx1) << 8;
    i4.z = (cy1 * 96 + cx0) << 8;
    i4.w = (cy1 * 96 + cx1) << 8;
    mw[u] = w4; mi[u] = i4;
  }
  __syncthreads();

  // ---- phase C: deform GEMM, double-buffered, 1 barrier / K-step ----
  const int ms = tid >> 3;    // staging row 0..15 (+16 for task 1)
  const int q = tid & 7;      // staging c-quad

  f32x4 acc[2][8];
#pragma unroll
  for (int a = 0; a < 2; ++a)
#pragma unroll
    for (int bb = 0; bb < 8; ++bb) acc[a][bb] = (f32x4){0.f, 0.f, 0.f, 0.f};

  // prologue: stage kb=0 into buf0
#pragma unroll
  for (int t2 = 0; t2 < 2; ++t2) {
    const int p = ms + t2 * 16;
    const float4 w4 = mw[p];
    const int4 i4 = mi[p];
    const int c = q * 4;
    const uint2 u00 = *(const uint2*)(xb + i4.x + c);
    const uint2 u01 = *(const uint2*)(xb + i4.y + c);
    const uint2 u10 = *(const uint2*)(xb + i4.z + c);
    const uint2 u11 = *(const uint2*)(xb + i4.w + c);
    short4 s4;
    s4.x = f2bf(w4.x * bflo(u00.x) + w4.y * bflo(u01.x) + w4.z * bflo(u10.x) + w4.w * bflo(u11.x));
    s4.y = f2bf(w4.x * bfhi(u00.x) + w4.y * bfhi(u01.x) + w4.z * bfhi(u10.x) + w4.w * bfhi(u11.x));
    s4.z = f2bf(w4.x * bflo(u00.y) + w4.y * bflo(u01.y) + w4.z * bflo(u10.y) + w4.w * bflo(u11.y));
    s4.w = f2bf(w4.x * bfhi(u00.y) + w4.y * bfhi(u01.y) + w4.z * bfhi(u10.y) + w4.w * bfhi(u11.y));
    *reinterpret_cast<short4*>(&vals[p * 40 + q * 4]) = s4;
  }
  __syncthreads();

  for (int kb = 0; kb < 72; ++kb) {
    const int cur = kb & 1;
    const short* vcur = vals + cur * 1280;
    short* vnxt = vals + (cur ^ 1) * 1280;

    // B-fragments (L2-resident, coalesced 16B/lane): 8 n-frags per wave
    bf16x8 bfr[8];
    const size_t wbase = ((size_t)(kb * 16 + wave * 8) * 64 + lane) * 8;
#pragma unroll
    for (int j = 0; j < 8; ++j)
      bfr[j] = *(const bf16x8*)(wfrag + wbase + (size_t)j * 512);

    // issue gathers for kb+1 early (overlap with MFMAs below)
    const int kbn = (kb < 71) ? kb + 1 : kb;
    const int kkn = kbn >> 3;
    const int c0n = (kbn & 7) << 5;
    uint2 U[2][4];
    float4 W4v[2];
#pragma unroll
    for (int t2 = 0; t2 < 2; ++t2) {
      const int p = ms + t2 * 16;
      W4v[t2] = mw[kkn * 32 + p];
      const int4 i4 = mi[kkn * 32 + p];
      const int c = c0n + q * 4;
      U[t2][0] = *(const uint2*)(xb + i4.x + c);
      U[t2][1] = *(const uint2*)(xb + i4.y + c);
      U[t2][2] = *(const uint2*)(xb + i4.z + c);
      U[t2][3] = *(const uint2*)(xb + i4.w + c);
    }

    // MFMAs on current buffer
#pragma unroll
    for (int mf = 0; mf < 2; ++mf) {
      const int row = mf * 16 + (lane & 15);
      const bf16x8 af = *(const bf16x8*)(&vcur[row * 40 + (lane >> 4) * 8]);
#pragma unroll
      for (int j = 0; j < 8; ++j)
        acc[mf][j] = __builtin_amdgcn_mfma_f32_16x16x32_bf16(af, bfr[j], acc[mf][j], 0, 0, 0);
    }

    // convert + write next buffer
    if (kb < 71) {
#pragma unroll
      for (int t2 = 0; t2 < 2; ++t2) {
        const int p = ms + t2 * 16;
        const float4 w4 = W4v[t2];
        short4 s4;
        s4.x = f2bf(w4.x * bflo(U[t2][0].x) + w4.y * bflo(U[t2][1].x) + w4.z * bflo(U[t2][2].x) + w4.w * bflo(U[t2][3].x));
        s4.y = f2bf(w4.x * bfhi(U[t2][0].x) + w4.y * bfhi(U[t2][1].x) + w4.z * bfhi(U[t2][2].x) + w4.w * bfhi(U[t2][3].x));
        s4.z = f2bf(w4.x * bflo(U[t2][0].y) + w4.y * bflo(U[t2][1].y) + w4.z * bflo(U[t2][2].y) + w4.w * bflo(U[t2][3].y));
        s4.w = f2bf(w4.x * bfhi(U[t2][0].y) + w4.y * bfhi(U[t2][1].y) + w4.z * bfhi(U[t2][2].y) + w4.w * bfhi(U[t2][3].y));
        *reinterpret_cast<short4*>(&vnxt[p * 40 + q * 4]) = s4;
      }
    }
    __syncthreads();
  }

  // ---- epilogue: D rows are 4 consecutive wo -> float4 stores ----
  const int col = lane & 15;
  const int rg = lane >> 4;
#pragma unroll
  for (int mf = 0; mf < 2; ++mf) {
    const int p = mf * 16 + rg * 4;
    const int wo = wo0 + p;
#pragma unroll
    for (int j = 0; j < 8; ++j) {
      const int o = wave * 128 + j * 16 + col;
      const float bv = db[o];
      float4 v;
      v.x = acc[mf][j][0] + bv;
      v.y = acc[mf][j][1] + bv;
      v.z = acc[mf][j][2] + bv;
      v.w = acc[mf][j][3] + bv;
      *(float4*)(out + (size_t)(b * 256 + o) * HW_ + ho0 * 96 + wo) = v;
    }
  }
}

extern "C" void kernel_launch(void* const* d_in, const int* in_sizes, int n_in,
                              void* d_out, int out_size, void* d_ws, size_t ws_size,
                              hipStream_t stream) {
  const float* x  = (const float*)d_in[0];
  const float* ow = (const float*)d_in[1];
  const float* ob = (const float*)d_in[2];
  const float* dw = (const float*)d_in[3];
  const float* db = (const float*)d_in[4];
  float* out = (float*)d_out;
  float* ws = (float*)d_ws;

  short* xt     = (short*)ws;                // 9,437,184 bf16 (18.9 MB)
  short* wfrag  = (short*)(ws + 4718592);    //   589,824 bf16
  short* owfrag = wfrag + 589824;            //    73,728 bf16  (~20.2 MB total)

  hipLaunchKernelGGL(k_transpose2, dim3(288, 8, 4), dim3(32, 8, 1), 0, stream, x, xt);
  hipLaunchKernelGGL(k_prep, dim3(2592), dim3(256), 0, stream, dw, ow, wfrag, owfrag);
  hipLaunchKernelGGL(k_deform, dim3(1152), dim3(128), 0, stream,
                     xt, wfrag, owfrag, ob, db, out);
}